// Round 3
// baseline (45.986 us; speedup 1.0000x reference)
//
#include <hip/hip_runtime.h>

// SpecAugment: out[b,m,t] = (freq_masked(b,m) || time_masked(b,t)) ? 0 : in[b,m,t]
// B=64, M=128, T=4000, fp32. Pure streaming, memory-bound.
// R3: non-temporal loads/stores via native ext_vector_type (HIP_vector_type
// rejected by the builtin).

constexpr int B_DIM = 64;
constexpr int M_DIM = 128;
constexpr int T_DIM = 4000;
constexpr int T4 = T_DIM / 4;                       // 1000 float4 per row
constexpr int TOTAL4 = B_DIM * M_DIM * T4;          // 8,192,000 float4s

typedef float f32x4 __attribute__((ext_vector_type(4)));

__global__ __launch_bounds__(256) void specaug_kernel(
    const f32x4* __restrict__ in,
    const int*   __restrict__ f,   // [2][B]
    const int*   __restrict__ f0,  // [2][B]
    const int*   __restrict__ t,   // [2][B]
    const int*   __restrict__ t0,  // [2][B]
    f32x4*       __restrict__ out)
{
    const int stride = gridDim.x * blockDim.x;
    for (int g = blockIdx.x * blockDim.x + threadIdx.x; g < TOTAL4; g += stride) {
        const int row = g / T4;            // magic-mul
        const int t4  = g - row * T4;
        const int b   = row >> 7;          // row / 128
        const int m   = row & 127;         // row % 128

        // frequency mask (uniform over the whole row)
        const int fA0 = f0[b],         fA = f[b];
        const int fB0 = f0[B_DIM + b], fB = f[B_DIM + b];
        const bool fm = ((unsigned)(m - fA0) < (unsigned)fA) |
                        ((unsigned)(m - fB0) < (unsigned)fB);

        f32x4 v;
        if (fm) {
            // whole row masked: skip the input read entirely
            v = (f32x4)(0.f);
        } else {
            v = __builtin_nontemporal_load(&in[g]);
            const int tA0 = t0[b],         tA = t[b];
            const int tB0 = t0[B_DIM + b], tB = t[B_DIM + b];
            const int tbase = t4 * 4;
            #pragma unroll
            for (int j = 0; j < 4; ++j) {
                const int tt = tbase + j;
                const bool tm = ((unsigned)(tt - tA0) < (unsigned)tA) |
                                ((unsigned)(tt - tB0) < (unsigned)tB);
                if (tm) v[j] = 0.f;
            }
        }
        __builtin_nontemporal_store(v, &out[g]);
    }
}

extern "C" void kernel_launch(void* const* d_in, const int* in_sizes, int n_in,
                              void* d_out, int out_size, void* d_ws, size_t ws_size,
                              hipStream_t stream) {
    const f32x4* in = (const f32x4*)d_in[0];
    const int*   f  = (const int*)d_in[1];
    const int*   f0 = (const int*)d_in[2];
    const int*   t  = (const int*)d_in[3];
    const int*   t0 = (const int*)d_in[4];
    f32x4*       out = (f32x4*)d_out;

    const int block = 256;
    const int grid  = 2048;   // 256 CU x 8 blocks/CU, grid-stride (~16 iters/thread)
    specaug_kernel<<<grid, block, 0, stream>>>(in, f, f0, t, t0, out);
}

// Round 4
// 40.068 us; speedup vs baseline: 1.1477x; 1.1477x over previous
//
#include <hip/hip_runtime.h>

// SpecAugment: out[b,m,t] = (freq_masked(b,m) || time_masked(b,t)) ? 0 : in[b,m,t]
// B=64, M=128, T=4000, fp32. Pure streaming, memory-bound.
// R4: revert to R1 (plain cached float4 load/store) — NT hints regressed
// 40.8 -> 46.0 us on gfx950 (L2 bypass lowers effective HBM bandwidth).

constexpr int B_DIM = 64;
constexpr int M_DIM = 128;
constexpr int T_DIM = 4000;
constexpr int T4 = T_DIM / 4;                       // 1000 float4 per row
constexpr int TOTAL4 = B_DIM * M_DIM * T4;          // 8,192,000 float4s

__global__ __launch_bounds__(256) void specaug_kernel(
    const float4* __restrict__ in,
    const int*    __restrict__ f,   // [2][B]
    const int*    __restrict__ f0,  // [2][B]
    const int*    __restrict__ t,   // [2][B]
    const int*    __restrict__ t0,  // [2][B]
    float4*       __restrict__ out)
{
    const int stride = gridDim.x * blockDim.x;
    for (int g = blockIdx.x * blockDim.x + threadIdx.x; g < TOTAL4; g += stride) {
        const int row = g / T4;            // magic-mul
        const int t4  = g - row * T4;
        const int b   = row >> 7;          // row / 128
        const int m   = row & 127;         // row % 128

        // frequency mask (uniform over the whole row)
        const int fA0 = f0[b],         fA = f[b];
        const int fB0 = f0[B_DIM + b], fB = f[B_DIM + b];
        const bool fm = ((unsigned)(m - fA0) < (unsigned)fA) |
                        ((unsigned)(m - fB0) < (unsigned)fB);

        float4 v;
        if (fm) {
            // whole row masked: skip the input read entirely
            v = make_float4(0.f, 0.f, 0.f, 0.f);
        } else {
            v = in[g];
            const int tA0 = t0[b],         tA = t[b];
            const int tB0 = t0[B_DIM + b], tB = t[B_DIM + b];
            const int tbase = t4 * 4;
            float* vp = &v.x;
            #pragma unroll
            for (int j = 0; j < 4; ++j) {
                const int tt = tbase + j;
                const bool tm = ((unsigned)(tt - tA0) < (unsigned)tA) |
                                ((unsigned)(tt - tB0) < (unsigned)tB);
                if (tm) vp[j] = 0.f;
            }
        }
        out[g] = v;
    }
}

extern "C" void kernel_launch(void* const* d_in, const int* in_sizes, int n_in,
                              void* d_out, int out_size, void* d_ws, size_t ws_size,
                              hipStream_t stream) {
    const float4* in = (const float4*)d_in[0];
    const int*    f  = (const int*)d_in[1];
    const int*    f0 = (const int*)d_in[2];
    const int*    t  = (const int*)d_in[3];
    const int*    t0 = (const int*)d_in[4];
    float4*       out = (float4*)d_out;

    const int block = 256;
    const int grid  = 2048;   // 256 CU x 8 blocks/CU, grid-stride (~16 iters/thread)
    specaug_kernel<<<grid, block, 0, stream>>>(in, f, f0, t, t0, out);
}